// Round 2
// baseline (259.987 us; speedup 1.0000x reference)
//
#include <hip/hip_runtime.h>
#include <math.h>

#define EPSF 1e-9f
#define KK 128
#define MTOP 10   // m

// R9 = R8 (tail/occupancy attack) with workspace footprint restored to the
// verified 2*B floats (R8 used 4*B and may have overflowed ws_size -> container
// death). Structure:
//  * 2 independent waves per 128-thread block, 2 blocks per b, grid 4096,
//    no barrier coupling during compute -> waves drift, scheduler back-fills,
//    straggler tail smooths (R7 counters: Occupancy 43% @ VALUBusy 42% with
//    one residency round = tail-bound, not pipe-bound).
//  * XCD-pairing swizzle: both blocks of a given b land on the same XCD
//    (same L2), dispatch-adjacent -> shared 64 KB P panel fetched once.
//  * Distance-1 register-pipelined P prefetch.
//  * Scalar epilogue (log2f/relu) in finalize_kernel.
//  * Block-local LDS max of the 2 wave hmax values -> hq[2*b+h] (2*B floats).
// LESSONS (R1-R7) preserved: compile-time-constant register-array indices,
// no helper-by-reference, load-into-scalars-consume-immediately, lockstep
// ballot bisection for the exact 11th-largest, no global atomics.
__global__ __launch_bounds__(128, 7) void fused_kernel(
    const float* __restrict__ P, const float* __restrict__ samples,
    float* __restrict__ hq /* [2*B]: hmax per (b, half) */)
{
    const int tid  = threadIdx.x;
    const int wave = tid >> 6;       // 0..1
    const int lane = tid & 63;

    // ---- XCD-pairing swizzle (assumes XCD = blockIdx % 8 round-robin) ----
    const int u = blockIdx.x;
    int b, h;
    if ((gridDim.x & 15) == 0) {
        const int perx = gridDim.x >> 4;        // b's per XCD
        b = (u & 7) * perx + (u >> 4);
        h = (u >> 3) & 1;
    } else {
        b = u >> 1;
        h = u & 1;
    }
    const int q  = h * 2 + wave;     // quarter 0..3 -> rows 5q..5q+4
    const int sg = lane >> 5;        // k-segment of the half-wave
    const int c  = lane & 31;        // column group
    const int j4 = c << 2;
    const int kbase = sg << 6;       // 0 or 64

    __shared__ float sS[2 * 5 * KK]; // per-wave private 5 rows
    __shared__ float redh[2];
    float* __restrict__ sW = sS + wave * (5 * KK);

    // ---- stage THIS WAVE's 5 sample rows, coalesced float2 ----
    const float* __restrict__ Sb = samples + ((size_t)b * 20 + q * 5) * KK;
#pragma unroll
    for (int i = 0; i < 5; ++i) {
        const int idx = i * KK + lane * 2;
        *(float2*)&sW[idx] = *(const float2*)(Sb + idx);
    }
    __syncthreads();   // cheap: 2 symmetric waves; drains the LDS writes

    float4 acc[5];
#pragma unroll
    for (int r = 0; r < 5; ++r) acc[r] = make_float4(0.f, 0.f, 0.f, 0.f);

    // ---- GEMM over this half-wave's 64 k values, software-pipelined ----
    const float* __restrict__ Pw = P + ((size_t)b << 14) + (size_t)kbase * KK + j4;
    float4 p0 = *(const float4*)(Pw + 0 * KK);
    float4 p1 = *(const float4*)(Pw + 1 * KK);
    float4 p2 = *(const float4*)(Pw + 2 * KK);
    float4 p3 = *(const float4*)(Pw + 3 * KK);
#pragma unroll
    for (int kk = 0; kk < 64; kk += 4) {
        float4 q0, q1, q2, q3;
        const bool pf = (kk + 4) < 64;          // compile-time after unroll
        if (pf) {
            const float* Pn = Pw + (size_t)(kk + 4) * KK;
            q0 = *(const float4*)(Pn + 0 * KK);
            q1 = *(const float4*)(Pn + 1 * KK);
            q2 = *(const float4*)(Pn + 2 * KK);
            q3 = *(const float4*)(Pn + 3 * KK);
        }
#pragma unroll
        for (int r = 0; r < 5; ++r) {
            float4 s = *(const float4*)&sW[r * KK + kbase + kk];
            acc[r].x = fmaf(s.x, p0.x, acc[r].x);
            acc[r].y = fmaf(s.x, p0.y, acc[r].y);
            acc[r].z = fmaf(s.x, p0.z, acc[r].z);
            acc[r].w = fmaf(s.x, p0.w, acc[r].w);
            acc[r].x = fmaf(s.y, p1.x, acc[r].x);
            acc[r].y = fmaf(s.y, p1.y, acc[r].y);
            acc[r].z = fmaf(s.y, p1.z, acc[r].z);
            acc[r].w = fmaf(s.y, p1.w, acc[r].w);
            acc[r].x = fmaf(s.z, p2.x, acc[r].x);
            acc[r].y = fmaf(s.z, p2.y, acc[r].y);
            acc[r].z = fmaf(s.z, p2.z, acc[r].z);
            acc[r].w = fmaf(s.z, p2.w, acc[r].w);
            acc[r].x = fmaf(s.w, p3.x, acc[r].x);
            acc[r].y = fmaf(s.w, p3.y, acc[r].y);
            acc[r].z = fmaf(s.w, p3.z, acc[r].z);
            acc[r].w = fmaf(s.w, p3.w, acc[r].w);
        }
        if (pf) { p0 = q0; p1 = q1; p2 = q2; p3 = q3; }
    }

    // ---- combine k-halves; upper half-wave switches to identity values ----
    float w0[5], w1[5], w2[5], w3[5];
#pragma unroll
    for (int r = 0; r < 5; ++r) {
        float ax = acc[r].x + __shfl_xor(acc[r].x, 32, 64);
        float ay = acc[r].y + __shfl_xor(acc[r].y, 32, 64);
        float az = acc[r].z + __shfl_xor(acc[r].z, 32, 64);
        float aw = acc[r].w + __shfl_xor(acc[r].w, 32, 64);
        float4 idv = *(const float4*)&sW[r * KK + j4];
        w0[r] = fabsf(sg ? idv.x : ax);
        w1[r] = fabsf(sg ? idv.y : ay);
        w2[r] = fabsf(sg ? idv.z : az);
        w3[r] = fabsf(sg ? idv.w : aw);
    }

    // ---- m1 per row: lane max + 6-shfl butterfly (5 chains interleave) ----
    float mx[5];
#pragma unroll
    for (int r = 0; r < 5; ++r) {
        float lm = fmaxf(fmaxf(w0[r], w1[r]), fmaxf(w2[r], w3[r]));
#pragma unroll
        for (int d = 32; d >= 1; d >>= 1)
            lm = fmaxf(lm, __shfl_xor(lm, d, 64));
        mx[r] = lm;
    }

    // ---- m11 per row: LOCKSTEP ballot bisection on float bit patterns ----
    unsigned lo[5], hi[5];
#pragma unroll
    for (int r = 0; r < 5; ++r) { lo[r] = 0u; hi[r] = __float_as_uint(mx[r]); }

    while (lo[0] < hi[0] || lo[1] < hi[1] || lo[2] < hi[2] ||
           lo[3] < hi[3] || lo[4] < hi[4]) {
#pragma unroll
        for (int r = 0; r < 5; ++r) {
            unsigned mid = lo[r] + ((hi[r] - lo[r] + 1u) >> 1);
            float mf = __uint_as_float(mid);
            int cnt = __popcll(__ballot(w0[r] > mf)) + __popcll(__ballot(w1[r] > mf))
                    + __popcll(__ballot(w2[r] > mf)) + __popcll(__ballot(w3[r] > mf));
            bool g = cnt >= (MTOP + 1);
            lo[r] = g ? mid : lo[r];
            hi[r] = g ? hi[r] : mid - 1u;
        }
    }

    float hmax = 0.f;
#pragma unroll
    for (int r = 0; r < 5; ++r) {
        float m11 = __uint_as_float(lo[r] + 1u);   // exact 11th-largest
        hmax = fmaxf(hmax, mx[r] / (m11 + EPSF));  // wave-uniform
    }

    // ---- combine the block's 2 waves; one float per (b, half) ----
    if (lane == 0) redh[wave] = hmax;
    __syncthreads();
    if (tid == 0) hq[2 * b + h] = fmaxf(redh[0], redh[1]);
}

__global__ __launch_bounds__(256) void finalize_kernel(
    const float* __restrict__ hq, const float* __restrict__ y_pred,
    const float* __restrict__ y_true, float* __restrict__ out,
    float invB, int B)
{
    const int t = threadIdx.x;
    float sl = 0.f, sp = 0.f;
    for (int bb = t; bb < B; bb += 256) {
        float2 h2 = *(const float2*)(hq + 2 * bb);
        float hb  = fmaxf(h2.x, h2.y);
        float ypv = y_pred[bb];
        float yp  = fmaxf(ypv, EPSF);
        float yt  = fmaxf(y_true[bb], EPSF);
        float d   = log2f(yt) - log2f(yp);
        sl += d * d;
        sp += fmaxf(hb - ypv, 0.f);
    }
#pragma unroll
    for (int d = 32; d >= 1; d >>= 1) {
        sl += __shfl_xor(sl, d, 64);
        sp += __shfl_xor(sp, d, 64);
    }
    __shared__ float rl[4], rp[4];
    const int w = t >> 6;
    if ((t & 63) == 0) { rl[w] = sl; rp[w] = sp; }
    __syncthreads();
    if (t == 0) {
        float L = (rl[0] + rl[1] + rl[2] + rl[3]) * invB;
        float V = (rp[0] + rp[1] + rp[2] + rp[3]) * invB;
        out[0] = L + 0.5f * V;
        out[1] = L;
        out[2] = V;
    }
}

extern "C" void kernel_launch(void* const* d_in, const int* in_sizes, int n_in,
                              void* d_out, int out_size, void* d_ws, size_t ws_size,
                              hipStream_t stream) {
    const float* y_pred  = (const float*)d_in[0];
    const float* y_true  = (const float*)d_in[1];
    const float* P       = (const float*)d_in[2];
    const float* samples = (const float*)d_in[3];
    const int B = in_sizes[0];           // y_pred has B elements

    float* hq = (float*)d_ws;            // 2*B floats, fully overwritten

    fused_kernel<<<2 * B, 128, 0, stream>>>(P, samples, hq);
    finalize_kernel<<<1, 256, 0, stream>>>(hq, y_pred, y_true, (float*)d_out,
                                           1.0f / (float)B, B);
}

// Round 3
// 230.846 us; speedup vs baseline: 1.1262x; 1.1262x over previous
//
#include <hip/hip_runtime.h>
#include <math.h>

#define EPSF 1e-9f
#define KK 128
#define MTOP 10   // m

// R10 = verified R7 structure (87 us fused, 236 us bench) + ONE change:
// a register-budgeted distance-1 software pipeline on the P loads.
//
// R9 post-mortem (103 us, REGRESSION): occupancy 43->58% but VALUBusy stuck
// at 42% and duration +18% -> residency was never the limiter. R9 also broke
// itself: full-unroll GEMM (~11KB body, I$ streaming) and launch_bounds(128,7)
// squeezed VGPRs to 36 so the prefetch could not allocate (p+q+acc > 36) and
// the compiler de-pipelined the loads.
//
// Theory now: R7 is latency-bound in the GEMM k-loop. With 44 VGPRs the
// unroll-2 body could not batch two 4-row load groups (32 VGPR loads + 20 acc
// > 44), so every 4-row group eats L2/L3 latency. This version keeps
// launch_bounds(256,4) (VGPR cap 128) and pipelines: load group kk+4, FMA
// group kk, swap. 15 pipelined iters + 1 epilogue, body ~1.6KB (I$-resident).
// Falsification check: VGPR_Count must come back >52, else the pipeline
// didn't allocate.
//
// LESSONS (R1-R9):
//  * Register arrays: compile-time-constant indices, unconditional writes.
//  * NEVER pass register arrays by reference to helpers (macros are fine).
//  * Load-into-scalars-consume-immediately, or explicit p/q scalar pipeline.
//  * Keep loop bodies small (no full unroll of the GEMM: I$ thrash).
//  * launch_bounds second arg caps VGPRs: (256,4) -> 128. Don't starve it.
//  * Workspace: 2*B floats proven safe; do not grow.
//  * Lockstep 5-row ballot bisection = exact 11th-largest; no global atomics.

#define FMA5(KKV)                                                          \
    _Pragma("unroll")                                                      \
    for (int r = 0; r < 5; ++r) {                                          \
        float4 s = *(const float4*)&sS[(r0 + r) * KK + kbase + (KKV)];     \
        acc[r].x = fmaf(s.x, p0.x, acc[r].x);                              \
        acc[r].y = fmaf(s.x, p0.y, acc[r].y);                              \
        acc[r].z = fmaf(s.x, p0.z, acc[r].z);                              \
        acc[r].w = fmaf(s.x, p0.w, acc[r].w);                              \
        acc[r].x = fmaf(s.y, p1.x, acc[r].x);                              \
        acc[r].y = fmaf(s.y, p1.y, acc[r].y);                              \
        acc[r].z = fmaf(s.y, p1.z, acc[r].z);                              \
        acc[r].w = fmaf(s.y, p1.w, acc[r].w);                              \
        acc[r].x = fmaf(s.z, p2.x, acc[r].x);                              \
        acc[r].y = fmaf(s.z, p2.y, acc[r].y);                              \
        acc[r].z = fmaf(s.z, p2.z, acc[r].z);                              \
        acc[r].w = fmaf(s.z, p2.w, acc[r].w);                              \
        acc[r].x = fmaf(s.w, p3.x, acc[r].x);                              \
        acc[r].y = fmaf(s.w, p3.y, acc[r].y);                              \
        acc[r].z = fmaf(s.w, p3.z, acc[r].z);                              \
        acc[r].w = fmaf(s.w, p3.w, acc[r].w);                              \
    }

__global__ __launch_bounds__(256, 4) void fused_kernel(
    const float* __restrict__ y_pred, const float* __restrict__ y_true,
    const float* __restrict__ P, const float* __restrict__ samples,
    float* __restrict__ partial /* [2*B]: per-block {logmse_i, penalty_i} */)
{
    const int tid   = threadIdx.x;
    const int wave  = tid >> 6;
    const int lane  = tid & 63;
    const int b     = blockIdx.x;
    const int r0    = wave * 5;
    const int sg    = lane >> 5;     // k-segment of the half-wave
    const int c     = lane & 31;     // column group
    const int j4    = c << 2;
    const int kbase = sg << 6;       // 0 or 64

    const float* __restrict__ Pb = P + ((size_t)b << 14);            // b*128*128
    const float* __restrict__ Sb = samples + (size_t)b * (20 * KK);  // b*20*128

    __shared__ float sS[20 * KK];   // S rows: GEMM broadcast + identity vals
    __shared__ float red[4];

    // ---- stage S into LDS, block-cooperative, coalesced float2 ----
#pragma unroll
    for (int i = 0; i < 5; ++i) {
        const int idx = (i * 256 + tid) * 2;
        *(float2*)&sS[idx] = *(const float2*)(Sb + idx);
    }
    __syncthreads();

    float4 acc[5];
#pragma unroll
    for (int r = 0; r < 5; ++r) acc[r] = make_float4(0.f, 0.f, 0.f, 0.f);

    // ---- GEMM over this half-wave's 64 k values ----
    // Distance-1 pipeline: group kk+4 loads in flight while group kk FMAs run.
    const float* __restrict__ Pw = Pb + (size_t)kbase * KK + j4;
    float4 p0 = *(const float4*)(Pw + 0 * KK);
    float4 p1 = *(const float4*)(Pw + 1 * KK);
    float4 p2 = *(const float4*)(Pw + 2 * KK);
    float4 p3 = *(const float4*)(Pw + 3 * KK);
#pragma unroll 1
    for (int kk = 0; kk < 60; kk += 4) {
        const float* __restrict__ Pn = Pw + (size_t)(kk + 4) * KK;
        float4 q0 = *(const float4*)(Pn + 0 * KK);
        float4 q1 = *(const float4*)(Pn + 1 * KK);
        float4 q2 = *(const float4*)(Pn + 2 * KK);
        float4 q3 = *(const float4*)(Pn + 3 * KK);
        FMA5(kk)
        p0 = q0; p1 = q1; p2 = q2; p3 = q3;
    }
    FMA5(60)   // epilogue group, no prefetch

    // ---- combine k-halves; upper half-wave switches to identity values ----
    // After the xor-add every lane holds the full sum for cols 4c..4c+3.
    // Lanes 32-63 then carry |S[r][4c..4c+3]| instead -> 256 values/row
    // distributed exactly once across the wave (4 per lane).
    float w0[5], w1[5], w2[5], w3[5];
#pragma unroll
    for (int r = 0; r < 5; ++r) {
        float ax = acc[r].x + __shfl_xor(acc[r].x, 32, 64);
        float ay = acc[r].y + __shfl_xor(acc[r].y, 32, 64);
        float az = acc[r].z + __shfl_xor(acc[r].z, 32, 64);
        float aw = acc[r].w + __shfl_xor(acc[r].w, 32, 64);
        float4 idv = *(const float4*)&sS[(r0 + r) * KK + j4];
        w0[r] = fabsf(sg ? idv.x : ax);
        w1[r] = fabsf(sg ? idv.y : ay);
        w2[r] = fabsf(sg ? idv.z : az);
        w3[r] = fabsf(sg ? idv.w : aw);
    }

    // ---- m1 per row: lane max + 6-shfl butterfly (5 chains interleave) ----
    float mx[5];
#pragma unroll
    for (int r = 0; r < 5; ++r) {
        float lm = fmaxf(fmaxf(w0[r], w1[r]), fmaxf(w2[r], w3[r]));
#pragma unroll
        for (int d = 32; d >= 1; d >>= 1)
            lm = fmaxf(lm, __shfl_xor(lm, d, 64));
        mx[r] = lm;
    }

    // ---- m11 per row: LOCKSTEP ballot bisection on float bit patterns ----
    // Invariant per row: pattern(m11) in [lo+1, hi+1]; converged rows take
    // the lo=mid branch forever (stable no-op), so lockstep is safe.
    unsigned lo[5], hi[5];
#pragma unroll
    for (int r = 0; r < 5; ++r) { lo[r] = 0u; hi[r] = __float_as_uint(mx[r]); }

    while (lo[0] < hi[0] || lo[1] < hi[1] || lo[2] < hi[2] ||
           lo[3] < hi[3] || lo[4] < hi[4]) {
#pragma unroll
        for (int r = 0; r < 5; ++r) {
            unsigned mid = lo[r] + ((hi[r] - lo[r] + 1u) >> 1);
            float mf = __uint_as_float(mid);
            int cnt = __popcll(__ballot(w0[r] > mf)) + __popcll(__ballot(w1[r] > mf))
                    + __popcll(__ballot(w2[r] > mf)) + __popcll(__ballot(w3[r] > mf));
            bool g = cnt >= (MTOP + 1);
            lo[r] = g ? mid : lo[r];
            hi[r] = g ? hi[r] : mid - 1u;
        }
    }

    float hmax = 0.f;
#pragma unroll
    for (int r = 0; r < 5; ++r) {
        float m11 = __uint_as_float(lo[r] + 1u);   // exact 11th-largest
        hmax = fmaxf(hmax, mx[r] / (m11 + EPSF));  // wave-uniform
    }

    // ---- combine 4 waves; per-block partials (no atomics) ----
    if (lane == 0) red[wave] = hmax;
    __syncthreads();
    if (tid == 0) {
        float hb  = fmaxf(fmaxf(red[0], red[1]), fmaxf(red[2], red[3]));
        float ypv = y_pred[b];
        float yp  = fmaxf(ypv, EPSF);
        float yt  = fmaxf(y_true[b], EPSF);
        float d   = log2f(yt) - log2f(yp);
        partial[2 * b]     = d * d;
        partial[2 * b + 1] = fmaxf(hb - ypv, 0.f);
    }
}

__global__ __launch_bounds__(256) void finalize_kernel(
    const float* __restrict__ partial, float* __restrict__ out, float invB)
{
    const int t = threadIdx.x;
    float sl = 0.f, sp = 0.f;
#pragma unroll
    for (int i = 0; i < 8; ++i) {
        float2 v = *(const float2*)(partial + 2 * (t + i * 256));
        sl += v.x; sp += v.y;
    }
#pragma unroll
    for (int d = 32; d >= 1; d >>= 1) {
        sl += __shfl_xor(sl, d, 64);
        sp += __shfl_xor(sp, d, 64);
    }
    __shared__ float rl[4], rp[4];
    const int w = t >> 6;
    if ((t & 63) == 0) { rl[w] = sl; rp[w] = sp; }
    __syncthreads();
    if (t == 0) {
        float L = (rl[0] + rl[1] + rl[2] + rl[3]) * invB;
        float V = (rp[0] + rp[1] + rp[2] + rp[3]) * invB;
        out[0] = L + 0.5f * V;
        out[1] = L;
        out[2] = V;
    }
}

extern "C" void kernel_launch(void* const* d_in, const int* in_sizes, int n_in,
                              void* d_out, int out_size, void* d_ws, size_t ws_size,
                              hipStream_t stream) {
    const float* y_pred  = (const float*)d_in[0];
    const float* y_true  = (const float*)d_in[1];
    const float* P       = (const float*)d_in[2];
    const float* samples = (const float*)d_in[3];
    const int B = in_sizes[0];           // y_pred has B elements

    float* partial = (float*)d_ws;       // 2*B floats, fully overwritten

    fused_kernel<<<B, 256, 0, stream>>>(y_pred, y_true, P, samples, partial);
    finalize_kernel<<<1, 256, 0, stream>>>(partial, (float*)d_out, 1.0f / (float)B);
}